// Round 1
// baseline (1037.262 us; speedup 1.0000x reference)
//
#include <hip/hip_runtime.h>

#define N_NODES 100000
#define N_EDGES 1600000
#define D 128

// ---------------- CSR build ----------------

__global__ __launch_bounds__(256) void hist_kernel(const int* __restrict__ dst,
                                                   int* __restrict__ counts) {
    int e = blockIdx.x * 256 + threadIdx.x;   // grid exactly N_EDGES
    atomicAdd(&counts[dst[e]], 1);
}

// Block-level exclusive scan (1024 elems/block), writes local scan + block sums.
__global__ __launch_bounds__(256) void scanA(const int* __restrict__ counts,
                                             int* __restrict__ row_ptr,
                                             int* __restrict__ blockSums) {
    __shared__ int sc[256];
    int tid  = threadIdx.x;
    int base = blockIdx.x * 1024 + tid * 4;
    int v[4];
#pragma unroll
    for (int k = 0; k < 4; ++k) {
        int i = base + k;
        v[k] = (i < N_NODES) ? counts[i] : 0;
    }
    int s = v[0] + v[1] + v[2] + v[3];
    sc[tid] = s;
    __syncthreads();
    for (int off = 1; off < 256; off <<= 1) {
        int t = (tid >= off) ? sc[tid - off] : 0;
        __syncthreads();
        sc[tid] += t;
        __syncthreads();
    }
    int run = sc[tid] - s;  // exclusive prefix of this thread within block
#pragma unroll
    for (int k = 0; k < 4; ++k) {
        int i = base + k;
        if (i < N_NODES) row_ptr[i] = run;
        run += v[k];
    }
    if (tid == 255) blockSums[blockIdx.x] = sc[255];
}

__global__ void scanB(int* blockSums, int nb) {
    if (threadIdx.x == 0 && blockIdx.x == 0) {
        int run = 0;
        for (int b = 0; b < nb; ++b) {
            int t = blockSums[b];
            blockSums[b] = run;
            run += t;
        }
    }
}

__global__ __launch_bounds__(256) void scanC(int* __restrict__ row_ptr,
                                             const int* __restrict__ blockSums) {
    int tid  = threadIdx.x;
    int base = blockIdx.x * 1024 + tid * 4;
    int add  = blockSums[blockIdx.x];
#pragma unroll
    for (int k = 0; k < 4; ++k) {
        int i = base + k;
        if (i < N_NODES) row_ptr[i] += add;
    }
    if (blockIdx.x == 0 && tid == 0) row_ptr[N_NODES] = N_EDGES;
}

__global__ __launch_bounds__(256) void fill_kernel(const int* __restrict__ src,
                                                   const int* __restrict__ dst,
                                                   const float* __restrict__ w,
                                                   const int* __restrict__ row_ptr,
                                                   int* __restrict__ cursor,
                                                   int* __restrict__ csr_src,
                                                   float* __restrict__ csr_w) {
    int e = blockIdx.x * 256 + threadIdx.x;   // grid exactly N_EDGES
    int d = dst[e];
    int p = row_ptr[d] + atomicAdd(&cursor[d], 1);
    csr_src[p] = src[e];
    csr_w[p]   = w[e];
}

// ---------------- weight transpose (Wt[k][j] = W[j][k]) ----------------

__global__ __launch_bounds__(256) void transpose_kernel(const float* __restrict__ W,
                                                        float* __restrict__ Wt) {
    int e = blockIdx.x * 256 + threadIdx.x;   // 16384 elems
    int r = e >> 7, k = e & 127;
    Wt[k * D + r] = W[e];
}

// ---------------- aggregation: one wave per node ----------------

__global__ __launch_bounds__(256) void aggregate_kernel(const float* __restrict__ h,
                                                        const int* __restrict__ row_ptr,
                                                        const int* __restrict__ csr_src,
                                                        const float* __restrict__ csr_w,
                                                        float* __restrict__ agg) {
    int node = blockIdx.x * 4 + (threadIdx.x >> 6);   // grid*4 == N_NODES exactly
    int lane = threadIdx.x & 63;
    int beg = row_ptr[node], end = row_ptr[node + 1];
    const float2* h2 = (const float2*)h;
    float2 acc = make_float2(0.f, 0.f);
    for (int e = beg; e < end; ++e) {
        int   s = csr_src[e];
        float w = csr_w[e];
        float2 v = h2[(size_t)s * 64 + lane];
        acc.x = fmaf(w, v.x, acc.x);
        acc.y = fmaf(w, v.y, acc.y);
    }
    ((float2*)agg)[(size_t)node * 64 + lane] = acc;
}

// ---------------- fused GEMM: out = agg@Wrel^T + h@Wroot^T + b (+ReLU) ----------------
// Wt_* are pre-transposed: Wt[k][j] = W[j][k].

__global__ __launch_bounds__(256) void gemm_fused(const float* __restrict__ agg,
                                                  const float* __restrict__ h,
                                                  const float* __restrict__ Wt_rel,
                                                  const float* __restrict__ Wt_root,
                                                  const float* __restrict__ bias,
                                                  float* __restrict__ out,
                                                  int relu) {
    __shared__ float sIn[32][256];   // [row][k]: k<128 agg, k>=128 h   (32 KB)
    __shared__ float sW[64][128];    // [kk][j] chunk of transposed W    (32 KB)
    int tid  = threadIdx.x;
    int row0 = blockIdx.x * 32;

    {   // stage 32 input rows (agg || h), float4-coalesced
        const float4* a4 = (const float4*)agg;
        const float4* h4 = (const float4*)h;
#pragma unroll
        for (int i = tid; i < 2048; i += 256) {
            int r = i >> 6, k4 = i & 63;
            float4 v = (k4 < 32) ? a4[(size_t)(row0 + r) * 32 + k4]
                                 : h4[(size_t)(row0 + r) * 32 + (k4 - 32)];
            *(float4*)&sIn[r][k4 * 4] = v;
        }
    }

    int tx = tid & 31;    // cols tx*4 .. tx*4+3
    int ty = tid >> 5;    // rows ty*4 .. ty*4+3
    float acc[4][4] = {};

    for (int kc = 0; kc < 4; ++kc) {
        const float* Wsrc = (kc < 2) ? Wt_rel : Wt_root;
        int krow0 = (kc & 1) * 64;
        __syncthreads();   // prior chunk's sW reads done (also covers sIn at kc=0)
#pragma unroll
        for (int i = tid; i < 2048; i += 256) {
            int kk = i >> 5, j4 = i & 31;
            *(float4*)&sW[kk][j4 * 4] = *(const float4*)&Wsrc[(krow0 + kk) * D + j4 * 4];
        }
        __syncthreads();
        int kbase = kc * 64;
#pragma unroll
        for (int kk = 0; kk < 64; kk += 4) {
            float4 a[4], w[4];
#pragma unroll
            for (int r = 0; r < 4; ++r) a[r] = *(float4*)&sIn[ty * 4 + r][kbase + kk];
#pragma unroll
            for (int d = 0; d < 4; ++d) w[d] = *(float4*)&sW[kk + d][tx * 4];
#define FMA4(AR, AS, WV)                      \
            AR[0] = fmaf(AS, WV.x, AR[0]);    \
            AR[1] = fmaf(AS, WV.y, AR[1]);    \
            AR[2] = fmaf(AS, WV.z, AR[2]);    \
            AR[3] = fmaf(AS, WV.w, AR[3]);
#pragma unroll
            for (int r = 0; r < 4; ++r) {
                FMA4(acc[r], a[r].x, w[0]);
                FMA4(acc[r], a[r].y, w[1]);
                FMA4(acc[r], a[r].z, w[2]);
                FMA4(acc[r], a[r].w, w[3]);
            }
#undef FMA4
        }
    }

    float4 bv = *(const float4*)&bias[tx * 4];
#pragma unroll
    for (int r = 0; r < 4; ++r) {
        int row = row0 + ty * 4 + r;
        float4 o;
        o.x = acc[r][0] + bv.x;
        o.y = acc[r][1] + bv.y;
        o.z = acc[r][2] + bv.z;
        o.w = acc[r][3] + bv.w;
        if (relu) {
            o.x = fmaxf(o.x, 0.f); o.y = fmaxf(o.y, 0.f);
            o.z = fmaxf(o.z, 0.f); o.w = fmaxf(o.w, 0.f);
        }
        *(float4*)&out[(size_t)row * D + tx * 4] = o;
    }
}

// ---------------- launch ----------------

extern "C" void kernel_launch(void* const* d_in, const int* in_sizes, int n_in,
                              void* d_out, int out_size, void* d_ws, size_t ws_size,
                              hipStream_t stream) {
    const float* x  = (const float*)d_in[0];
    const float* ew = (const float*)d_in[1];
    const float* W_rel[3]  = {(const float*)d_in[2], (const float*)d_in[5], (const float*)d_in[8]};
    const float* W_root[3] = {(const float*)d_in[3], (const float*)d_in[6], (const float*)d_in[9]};
    const float* bias[3]   = {(const float*)d_in[4], (const float*)d_in[7], (const float*)d_in[10]};
    const int* esrc = (const int*)d_in[11];
    const int* edst = (const int*)d_in[12];
    float* out = (float*)d_out;

    char* ws = (char*)d_ws;
    float* agg       = (float*)(ws);                 // 51,200,000 B
    float* h1        = (float*)(ws + 51200000);      // 51,200,000 B
    int*   csr_src   = (int*)  (ws + 102400000);     //  6,400,000 B
    float* csr_w     = (float*)(ws + 108800000);     //  6,400,000 B
    int*   row_ptr   = (int*)  (ws + 115200000);     //    400,016 B
    int*   cursor    = (int*)  (ws + 115600016);     //    400,000 B
    int*   blockSums = (int*)  (ws + 116000016);     //        512 B
    float* Wt        = (float*)(ws + 116000528);     //    393,216 B  (6 x 128x128)
    // total ~116.4 MB of d_ws

    // CSR build (once per launch, reused by all 3 layers)
    hipMemsetAsync(cursor, 0, N_NODES * sizeof(int), stream);
    hist_kernel<<<N_EDGES / 256, 256, 0, stream>>>(edst, cursor);
    scanA<<<98, 256, 0, stream>>>(cursor, row_ptr, blockSums);
    scanB<<<1, 64, 0, stream>>>(blockSums, 98);
    scanC<<<98, 256, 0, stream>>>(row_ptr, blockSums);
    hipMemsetAsync(cursor, 0, N_NODES * sizeof(int), stream);
    fill_kernel<<<N_EDGES / 256, 256, 0, stream>>>(esrc, edst, ew, row_ptr, cursor,
                                                   csr_src, csr_w);
    // weight transposes
    for (int l = 0; l < 3; ++l) {
        transpose_kernel<<<64, 256, 0, stream>>>(W_rel[l],  Wt + (2 * l)     * 16384);
        transpose_kernel<<<64, 256, 0, stream>>>(W_root[l], Wt + (2 * l + 1) * 16384);
    }

    // 3 GraphConv layers: x -> h1 -> out -> out(in-place rows)
    const float* hin = x;
    for (int l = 0; l < 3; ++l) {
        float* hout = (l == 0) ? h1 : out;
        aggregate_kernel<<<N_NODES / 4, 256, 0, stream>>>(hin, row_ptr, csr_src, csr_w, agg);
        gemm_fused<<<N_NODES / 32, 256, 0, stream>>>(agg, hin,
                                                     Wt + (2 * l) * 16384,
                                                     Wt + (2 * l + 1) * 16384,
                                                     bias[l], hout, (l < 2) ? 1 : 0);
        hin = hout;
    }
}

// Round 2
// 887.957 us; speedup vs baseline: 1.1681x; 1.1681x over previous
//
#include <hip/hip_runtime.h>

#define N_NODES 100000
#define N_EDGES 1600000
#define D 128

// ---------------- CSR build ----------------

__global__ __launch_bounds__(256) void hist_kernel(const int* __restrict__ dst,
                                                   int* __restrict__ counts) {
    int e = blockIdx.x * 256 + threadIdx.x;   // grid exactly N_EDGES
    atomicAdd(&counts[dst[e]], 1);
}

// Block-level exclusive scan (1024 elems/block), writes local scan + block sums.
__global__ __launch_bounds__(256) void scanA(const int* __restrict__ counts,
                                             int* __restrict__ row_ptr,
                                             int* __restrict__ blockSums) {
    __shared__ int sc[256];
    int tid  = threadIdx.x;
    int base = blockIdx.x * 1024 + tid * 4;
    int v[4];
#pragma unroll
    for (int k = 0; k < 4; ++k) {
        int i = base + k;
        v[k] = (i < N_NODES) ? counts[i] : 0;
    }
    int s = v[0] + v[1] + v[2] + v[3];
    sc[tid] = s;
    __syncthreads();
    for (int off = 1; off < 256; off <<= 1) {
        int t = (tid >= off) ? sc[tid - off] : 0;
        __syncthreads();
        sc[tid] += t;
        __syncthreads();
    }
    int run = sc[tid] - s;  // exclusive prefix of this thread within block
#pragma unroll
    for (int k = 0; k < 4; ++k) {
        int i = base + k;
        if (i < N_NODES) row_ptr[i] = run;
        run += v[k];
    }
    if (tid == 255) blockSums[blockIdx.x] = sc[255];
}

__global__ void scanB(int* blockSums, int nb) {
    if (threadIdx.x == 0 && blockIdx.x == 0) {
        int run = 0;
        for (int b = 0; b < nb; ++b) {
            int t = blockSums[b];
            blockSums[b] = run;
            run += t;
        }
    }
}

__global__ __launch_bounds__(256) void scanC(int* __restrict__ row_ptr,
                                             const int* __restrict__ blockSums) {
    int tid  = threadIdx.x;
    int base = blockIdx.x * 1024 + tid * 4;
    int add  = blockSums[blockIdx.x];
#pragma unroll
    for (int k = 0; k < 4; ++k) {
        int i = base + k;
        if (i < N_NODES) row_ptr[i] += add;
    }
    if (blockIdx.x == 0 && tid == 0) row_ptr[N_NODES] = N_EDGES;
}

// csr_sw[p] = (src, float_as_int(w)) — one 8B uniform load per edge in aggregate.
__global__ __launch_bounds__(256) void fill_kernel(const int* __restrict__ src,
                                                   const int* __restrict__ dst,
                                                   const float* __restrict__ w,
                                                   const int* __restrict__ row_ptr,
                                                   int* __restrict__ cursor,
                                                   int2* __restrict__ csr_sw) {
    int e = blockIdx.x * 256 + threadIdx.x;   // grid exactly N_EDGES
    int d = dst[e];
    int p = row_ptr[d] + atomicAdd(&cursor[d], 1);
    csr_sw[p] = make_int2(src[e], __float_as_int(w[e]));
}

// ---------------- weight transpose (Wt[k][j] = W[j][k]) ----------------

__global__ __launch_bounds__(256) void transpose_kernel(const float* __restrict__ W,
                                                        float* __restrict__ Wt) {
    int e = blockIdx.x * 256 + threadIdx.x;   // 16384 elems
    int r = e >> 7, k = e & 127;
    Wt[k * D + r] = W[e];
}

// ---------------- aggregation: one wave per node, 8 gathers in flight ----------------

__global__ __launch_bounds__(256) void aggregate_kernel(const float* __restrict__ h,
                                                        const int* __restrict__ row_ptr,
                                                        const int2* __restrict__ csr_sw,
                                                        float* __restrict__ agg) {
    int node = blockIdx.x * 4 + (threadIdx.x >> 6);   // grid*4 == N_NODES exactly
    int lane = threadIdx.x & 63;
    int beg = row_ptr[node], end = row_ptr[node + 1];
    const float2* h2 = (const float2*)h;

    float2 acc0 = make_float2(0.f, 0.f);
    float2 acc1 = make_float2(0.f, 0.f);

    int e = beg;
    for (; e + 8 <= end; e += 8) {
        int2 p0 = csr_sw[e + 0], p1 = csr_sw[e + 1], p2 = csr_sw[e + 2], p3 = csr_sw[e + 3];
        int2 p4 = csr_sw[e + 4], p5 = csr_sw[e + 5], p6 = csr_sw[e + 6], p7 = csr_sw[e + 7];
        float2 v0 = h2[(size_t)p0.x * 64 + lane];
        float2 v1 = h2[(size_t)p1.x * 64 + lane];
        float2 v2 = h2[(size_t)p2.x * 64 + lane];
        float2 v3 = h2[(size_t)p3.x * 64 + lane];
        float2 v4 = h2[(size_t)p4.x * 64 + lane];
        float2 v5 = h2[(size_t)p5.x * 64 + lane];
        float2 v6 = h2[(size_t)p6.x * 64 + lane];
        float2 v7 = h2[(size_t)p7.x * 64 + lane];
        float w0 = __int_as_float(p0.y), w1 = __int_as_float(p1.y);
        float w2 = __int_as_float(p2.y), w3 = __int_as_float(p3.y);
        float w4 = __int_as_float(p4.y), w5 = __int_as_float(p5.y);
        float w6 = __int_as_float(p6.y), w7 = __int_as_float(p7.y);
        acc0.x = fmaf(w0, v0.x, acc0.x); acc0.y = fmaf(w0, v0.y, acc0.y);
        acc1.x = fmaf(w1, v1.x, acc1.x); acc1.y = fmaf(w1, v1.y, acc1.y);
        acc0.x = fmaf(w2, v2.x, acc0.x); acc0.y = fmaf(w2, v2.y, acc0.y);
        acc1.x = fmaf(w3, v3.x, acc1.x); acc1.y = fmaf(w3, v3.y, acc1.y);
        acc0.x = fmaf(w4, v4.x, acc0.x); acc0.y = fmaf(w4, v4.y, acc0.y);
        acc1.x = fmaf(w5, v5.x, acc1.x); acc1.y = fmaf(w5, v5.y, acc1.y);
        acc0.x = fmaf(w6, v6.x, acc0.x); acc0.y = fmaf(w6, v6.y, acc0.y);
        acc1.x = fmaf(w7, v7.x, acc1.x); acc1.y = fmaf(w7, v7.y, acc1.y);
    }
    // tail (up to 7 edges): still batch-issue loads before consuming
    {
        int rem = end - e;
        int2   p[7];
        float2 v[7];
#pragma unroll
        for (int k = 0; k < 7; ++k)
            if (k < rem) p[k] = csr_sw[e + k];
#pragma unroll
        for (int k = 0; k < 7; ++k)
            if (k < rem) v[k] = h2[(size_t)p[k].x * 64 + lane];
#pragma unroll
        for (int k = 0; k < 7; ++k)
            if (k < rem) {
                float w = __int_as_float(p[k].y);
                acc0.x = fmaf(w, v[k].x, acc0.x);
                acc0.y = fmaf(w, v[k].y, acc0.y);
            }
    }
    float2 acc = make_float2(acc0.x + acc1.x, acc0.y + acc1.y);
    ((float2*)agg)[(size_t)node * 64 + lane] = acc;
}

// ---------------- fused GEMM: out = agg@Wrel^T + h@Wroot^T + b (+ReLU) ----------------
// Wt_* are pre-transposed: Wt[k][j] = W[j][k].

__global__ __launch_bounds__(256) void gemm_fused(const float* __restrict__ agg,
                                                  const float* __restrict__ h,
                                                  const float* __restrict__ Wt_rel,
                                                  const float* __restrict__ Wt_root,
                                                  const float* __restrict__ bias,
                                                  float* __restrict__ out,
                                                  int relu) {
    __shared__ float sIn[32][256];   // [row][k]: k<128 agg, k>=128 h   (32 KB)
    __shared__ float sW[64][128];    // [kk][j] chunk of transposed W    (32 KB)
    int tid  = threadIdx.x;
    int row0 = blockIdx.x * 32;

    {   // stage 32 input rows (agg || h), float4-coalesced
        const float4* a4 = (const float4*)agg;
        const float4* h4 = (const float4*)h;
#pragma unroll
        for (int i = tid; i < 2048; i += 256) {
            int r = i >> 6, k4 = i & 63;
            float4 v = (k4 < 32) ? a4[(size_t)(row0 + r) * 32 + k4]
                                 : h4[(size_t)(row0 + r) * 32 + (k4 - 32)];
            *(float4*)&sIn[r][k4 * 4] = v;
        }
    }

    int tx = tid & 31;    // cols tx*4 .. tx*4+3
    int ty = tid >> 5;    // rows ty*4 .. ty*4+3
    float acc[4][4] = {};

    for (int kc = 0; kc < 4; ++kc) {
        const float* Wsrc = (kc < 2) ? Wt_rel : Wt_root;
        int krow0 = (kc & 1) * 64;
        __syncthreads();   // prior chunk's sW reads done (also covers sIn at kc=0)
#pragma unroll
        for (int i = tid; i < 2048; i += 256) {
            int kk = i >> 5, j4 = i & 31;
            *(float4*)&sW[kk][j4 * 4] = *(const float4*)&Wsrc[(krow0 + kk) * D + j4 * 4];
        }
        __syncthreads();
        int kbase = kc * 64;
#pragma unroll
        for (int kk = 0; kk < 64; kk += 4) {
            float4 a[4], w[4];
#pragma unroll
            for (int r = 0; r < 4; ++r) a[r] = *(float4*)&sIn[ty * 4 + r][kbase + kk];
#pragma unroll
            for (int d = 0; d < 4; ++d) w[d] = *(float4*)&sW[kk + d][tx * 4];
#define FMA4(AR, AS, WV)                      \
            AR[0] = fmaf(AS, WV.x, AR[0]);    \
            AR[1] = fmaf(AS, WV.y, AR[1]);    \
            AR[2] = fmaf(AS, WV.z, AR[2]);    \
            AR[3] = fmaf(AS, WV.w, AR[3]);
#pragma unroll
            for (int r = 0; r < 4; ++r) {
                FMA4(acc[r], a[r].x, w[0]);
                FMA4(acc[r], a[r].y, w[1]);
                FMA4(acc[r], a[r].z, w[2]);
                FMA4(acc[r], a[r].w, w[3]);
            }
#undef FMA4
        }
    }

    float4 bv = *(const float4*)&bias[tx * 4];
#pragma unroll
    for (int r = 0; r < 4; ++r) {
        int row = row0 + ty * 4 + r;
        float4 o;
        o.x = acc[r][0] + bv.x;
        o.y = acc[r][1] + bv.y;
        o.z = acc[r][2] + bv.z;
        o.w = acc[r][3] + bv.w;
        if (relu) {
            o.x = fmaxf(o.x, 0.f); o.y = fmaxf(o.y, 0.f);
            o.z = fmaxf(o.z, 0.f); o.w = fmaxf(o.w, 0.f);
        }
        *(float4*)&out[(size_t)row * D + tx * 4] = o;
    }
}

// ---------------- launch ----------------

extern "C" void kernel_launch(void* const* d_in, const int* in_sizes, int n_in,
                              void* d_out, int out_size, void* d_ws, size_t ws_size,
                              hipStream_t stream) {
    const float* x  = (const float*)d_in[0];
    const float* ew = (const float*)d_in[1];
    const float* W_rel[3]  = {(const float*)d_in[2], (const float*)d_in[5], (const float*)d_in[8]};
    const float* W_root[3] = {(const float*)d_in[3], (const float*)d_in[6], (const float*)d_in[9]};
    const float* bias[3]   = {(const float*)d_in[4], (const float*)d_in[7], (const float*)d_in[10]};
    const int* esrc = (const int*)d_in[11];
    const int* edst = (const int*)d_in[12];
    float* out = (float*)d_out;

    char* ws = (char*)d_ws;
    float* agg       = (float*)(ws);                 // 51,200,000 B
    float* h1        = (float*)(ws + 51200000);      // 51,200,000 B
    int2*  csr_sw    = (int2*) (ws + 102400000);     // 12,800,000 B
    int*   row_ptr   = (int*)  (ws + 115200000);     //    400,016 B
    int*   cursor    = (int*)  (ws + 115600016);     //    400,000 B
    int*   blockSums = (int*)  (ws + 116000016);     //        512 B
    float* Wt        = (float*)(ws + 116000528);     //    393,216 B  (6 x 128x128)
    // total ~116.4 MB of d_ws

    // CSR build (once per launch, reused by all 3 layers)
    hipMemsetAsync(cursor, 0, N_NODES * sizeof(int), stream);
    hist_kernel<<<N_EDGES / 256, 256, 0, stream>>>(edst, cursor);
    scanA<<<98, 256, 0, stream>>>(cursor, row_ptr, blockSums);
    scanB<<<1, 64, 0, stream>>>(blockSums, 98);
    scanC<<<98, 256, 0, stream>>>(row_ptr, blockSums);
    hipMemsetAsync(cursor, 0, N_NODES * sizeof(int), stream);
    fill_kernel<<<N_EDGES / 256, 256, 0, stream>>>(esrc, edst, ew, row_ptr, cursor, csr_sw);
    // weight transposes
    for (int l = 0; l < 3; ++l) {
        transpose_kernel<<<64, 256, 0, stream>>>(W_rel[l],  Wt + (2 * l)     * 16384);
        transpose_kernel<<<64, 256, 0, stream>>>(W_root[l], Wt + (2 * l + 1) * 16384);
    }

    // 3 GraphConv layers: x -> h1 -> out -> out(in-place rows)
    const float* hin = x;
    for (int l = 0; l < 3; ++l) {
        float* hout = (l == 0) ? h1 : out;
        aggregate_kernel<<<N_NODES / 4, 256, 0, stream>>>(hin, row_ptr, csr_sw, agg);
        gemm_fused<<<N_NODES / 32, 256, 0, stream>>>(agg, hin,
                                                     Wt + (2 * l) * 16384,
                                                     Wt + (2 * l + 1) * 16384,
                                                     bias[l], hout, (l < 2) ? 1 : 0);
        hin = hout;
    }
}

// Round 3
// 618.110 us; speedup vs baseline: 1.6781x; 1.4366x over previous
//
#include <hip/hip_runtime.h>

#define N_NODES 100000
#define N_EDGES 1600000
#define D 128
#define N_TILES 3125        // N_NODES / 32
#define GEMM_GRID 512

typedef _Float16 f16;
typedef _Float16 f16x8 __attribute__((ext_vector_type(8)));
typedef _Float16 f16x4 __attribute__((ext_vector_type(4)));
typedef float f32x4 __attribute__((ext_vector_type(4)));

// ---------------- CSR build ----------------

__global__ __launch_bounds__(256) void hist_kernel(const int* __restrict__ dst,
                                                   int* __restrict__ counts) {
    int e = blockIdx.x * 256 + threadIdx.x;   // grid exactly N_EDGES
    atomicAdd(&counts[dst[e]], 1);
}

__global__ __launch_bounds__(256) void scanA(const int* __restrict__ counts,
                                             int* __restrict__ row_ptr,
                                             int* __restrict__ blockSums) {
    __shared__ int sc[256];
    int tid  = threadIdx.x;
    int base = blockIdx.x * 1024 + tid * 4;
    int v[4];
#pragma unroll
    for (int k = 0; k < 4; ++k) {
        int i = base + k;
        v[k] = (i < N_NODES) ? counts[i] : 0;
    }
    int s = v[0] + v[1] + v[2] + v[3];
    sc[tid] = s;
    __syncthreads();
    for (int off = 1; off < 256; off <<= 1) {
        int t = (tid >= off) ? sc[tid - off] : 0;
        __syncthreads();
        sc[tid] += t;
        __syncthreads();
    }
    int run = sc[tid] - s;
#pragma unroll
    for (int k = 0; k < 4; ++k) {
        int i = base + k;
        if (i < N_NODES) row_ptr[i] = run;
        run += v[k];
    }
    if (tid == 255) blockSums[blockIdx.x] = sc[255];
}

__global__ void scanB(int* blockSums, int nb) {
    if (threadIdx.x == 0 && blockIdx.x == 0) {
        int run = 0;
        for (int b = 0; b < nb; ++b) {
            int t = blockSums[b];
            blockSums[b] = run;
            run += t;
        }
    }
}

__global__ __launch_bounds__(256) void scanC(int* __restrict__ row_ptr,
                                             const int* __restrict__ blockSums) {
    int tid  = threadIdx.x;
    int base = blockIdx.x * 1024 + tid * 4;
    int add  = blockSums[blockIdx.x];
#pragma unroll
    for (int k = 0; k < 4; ++k) {
        int i = base + k;
        if (i < N_NODES) row_ptr[i] += add;
    }
    if (blockIdx.x == 0 && tid == 0) row_ptr[N_NODES] = N_EDGES;
}

// csr_sw[p] = (src, float_as_int(w))
__global__ __launch_bounds__(256) void fill_kernel(const int* __restrict__ src,
                                                   const int* __restrict__ dst,
                                                   const float* __restrict__ w,
                                                   const int* __restrict__ row_ptr,
                                                   int* __restrict__ cursor,
                                                   int2* __restrict__ csr_sw) {
    int e = blockIdx.x * 256 + threadIdx.x;   // grid exactly N_EDGES
    int d = dst[e];
    int p = row_ptr[d] + atomicAdd(&cursor[d], 1);
    csr_sw[p] = make_int2(src[e], __float_as_int(w[e]));
}

// ---------------- weight pack: B-fragment layout, f16 ----------------
// Bp element ((ks*8 + ct)*64 + lane)*8 + e = W[j][k] with
// j = ct*16 + (lane&15), k = ks*32 + (lane>>4)*8 + e  (k<128 -> Wrel, else Wroot)

__global__ __launch_bounds__(256) void pack_weights(const float* __restrict__ Wrel,
                                                    const float* __restrict__ Wroot,
                                                    f16* __restrict__ Bp) {
    int idx = blockIdx.x * 256 + threadIdx.x;   // 32768 total -> 128 blocks
    int e = idx & 7, lane = (idx >> 3) & 63, ct = (idx >> 9) & 7, ks = idx >> 12;
    int j = ct * 16 + (lane & 15);
    int k = ks * 32 + (lane >> 4) * 8 + e;
    float w = (k < D) ? Wrel[j * D + k] : Wroot[j * D + (k - D)];
    Bp[idx] = (f16)w;
}

// ---------------- aggregation: one wave per node, 8 gathers in flight ----------------

__global__ __launch_bounds__(256) void aggregate_kernel(const float* __restrict__ h,
                                                        const int* __restrict__ row_ptr,
                                                        const int2* __restrict__ csr_sw,
                                                        float* __restrict__ agg) {
    int node = blockIdx.x * 4 + (threadIdx.x >> 6);
    int lane = threadIdx.x & 63;
    int beg = row_ptr[node], end = row_ptr[node + 1];
    const float2* h2 = (const float2*)h;

    float2 acc0 = make_float2(0.f, 0.f);
    float2 acc1 = make_float2(0.f, 0.f);

    int e = beg;
    for (; e + 8 <= end; e += 8) {
        int2 p0 = csr_sw[e + 0], p1 = csr_sw[e + 1], p2 = csr_sw[e + 2], p3 = csr_sw[e + 3];
        int2 p4 = csr_sw[e + 4], p5 = csr_sw[e + 5], p6 = csr_sw[e + 6], p7 = csr_sw[e + 7];
        float2 v0 = h2[(size_t)p0.x * 64 + lane];
        float2 v1 = h2[(size_t)p1.x * 64 + lane];
        float2 v2 = h2[(size_t)p2.x * 64 + lane];
        float2 v3 = h2[(size_t)p3.x * 64 + lane];
        float2 v4 = h2[(size_t)p4.x * 64 + lane];
        float2 v5 = h2[(size_t)p5.x * 64 + lane];
        float2 v6 = h2[(size_t)p6.x * 64 + lane];
        float2 v7 = h2[(size_t)p7.x * 64 + lane];
        float w0 = __int_as_float(p0.y), w1 = __int_as_float(p1.y);
        float w2 = __int_as_float(p2.y), w3 = __int_as_float(p3.y);
        float w4 = __int_as_float(p4.y), w5 = __int_as_float(p5.y);
        float w6 = __int_as_float(p6.y), w7 = __int_as_float(p7.y);
        acc0.x = fmaf(w0, v0.x, acc0.x); acc0.y = fmaf(w0, v0.y, acc0.y);
        acc1.x = fmaf(w1, v1.x, acc1.x); acc1.y = fmaf(w1, v1.y, acc1.y);
        acc0.x = fmaf(w2, v2.x, acc0.x); acc0.y = fmaf(w2, v2.y, acc0.y);
        acc1.x = fmaf(w3, v3.x, acc1.x); acc1.y = fmaf(w3, v3.y, acc1.y);
        acc0.x = fmaf(w4, v4.x, acc0.x); acc0.y = fmaf(w4, v4.y, acc0.y);
        acc1.x = fmaf(w5, v5.x, acc1.x); acc1.y = fmaf(w5, v5.y, acc1.y);
        acc0.x = fmaf(w6, v6.x, acc0.x); acc0.y = fmaf(w6, v6.y, acc0.y);
        acc1.x = fmaf(w7, v7.x, acc1.x); acc1.y = fmaf(w7, v7.y, acc1.y);
    }
    {
        int rem = end - e;
        int2   p[7];
        float2 v[7];
#pragma unroll
        for (int k = 0; k < 7; ++k)
            if (k < rem) p[k] = csr_sw[e + k];
#pragma unroll
        for (int k = 0; k < 7; ++k)
            if (k < rem) v[k] = h2[(size_t)p[k].x * 64 + lane];
#pragma unroll
        for (int k = 0; k < 7; ++k)
            if (k < rem) {
                float w = __int_as_float(p[k].y);
                acc0.x = fmaf(w, v[k].x, acc0.x);
                acc0.y = fmaf(w, v[k].y, acc0.y);
            }
    }
    float2 acc = make_float2(acc0.x + acc1.x, acc0.y + acc1.y);
    ((float2*)agg)[(size_t)node * 64 + lane] = acc;
}

// ---------------- MFMA GEMM: out = [agg|h] @ Bp + bias (+ReLU) ----------------
// 256 thr = 4 waves (2 row x 2 col). Wave owns 16 rows x 64 cols.
// B-frags in registers (loaded once). A staged f16 in LDS, XOR-swizzled,
// double-buffered, grid-stride over 32-row tiles.

__global__ __launch_bounds__(256, 2) void gemm_mfma(const float* __restrict__ agg,
                                                    const float* __restrict__ h,
                                                    const f16x8* __restrict__ Bp,
                                                    const float* __restrict__ bias,
                                                    float* __restrict__ out,
                                                    int relu) {
    __shared__ f16 sA[2][32 * 256];   // 2 x 16 KB
    int tid  = threadIdx.x;
    int lane = tid & 63;
    int wid  = tid >> 6;
    int wrow = wid >> 1;              // rows [wrow*16, +16)
    int wcol = wid & 1;               // cols [wcol*64, +64)

    // B fragments: 8 k-steps x 4 col-tiles, 128 VGPRs, loaded once (L2-hot)
    f16x8 breg[8][4];
#pragma unroll
    for (int ks = 0; ks < 8; ++ks)
#pragma unroll
        for (int c = 0; c < 4; ++c)
            breg[ks][c] = Bp[(ks * 8 + wcol * 4 + c) * 64 + lane];

    float bv[4];
#pragma unroll
    for (int c = 0; c < 4; ++c) bv[c] = bias[wcol * 64 + c * 16 + (lane & 15)];

    const float4* a4 = (const float4*)agg;
    const float4* h4 = (const float4*)h;

    // prologue: stage first tile into buf 0
    {
        int row0 = blockIdx.x * 32;
#pragma unroll
        for (int it = 0; it < 8; ++it) {
            int i = it * 256 + tid, r = i >> 6, k4 = i & 63;
            float4 v = (k4 < 32) ? a4[(row0 + r) * 32 + k4]
                                 : h4[(row0 + r) * 32 + (k4 - 32)];
            f16x4 hv;
            hv[0] = (f16)v.x; hv[1] = (f16)v.y; hv[2] = (f16)v.z; hv[3] = (f16)v.w;
            int o = (r * 256 + k4 * 4) ^ ((r & 7) << 3);
            *(f16x4*)&sA[0][o] = hv;
        }
    }
    __syncthreads();

    int buf = 0;
    for (int t = blockIdx.x; t < N_TILES; t += GEMM_GRID) {
        int  tn = t + GEMM_GRID;
        bool havenext = (tn < N_TILES);

        // issue next tile's global loads early (latency hides under MFMA)
        float4 sreg[8];
        if (havenext) {
            int row0 = tn * 32;
#pragma unroll
            for (int it = 0; it < 8; ++it) {
                int i = it * 256 + tid, r = i >> 6, k4 = i & 63;
                sreg[it] = (k4 < 32) ? a4[(row0 + r) * 32 + k4]
                                     : h4[(row0 + r) * 32 + (k4 - 32)];
            }
        }

        // compute tile t from sA[buf]
        f32x4 acc[4] = {f32x4{0,0,0,0}, f32x4{0,0,0,0}, f32x4{0,0,0,0}, f32x4{0,0,0,0}};
        int arow = wrow * 16 + (lane & 15);
        int kg   = (lane >> 4) * 8;
#pragma unroll
        for (int ks = 0; ks < 8; ++ks) {
            int o = (arow * 256 + ks * 32 + kg) ^ ((arow & 7) << 3);
            f16x8 afrag = *(const f16x8*)&sA[buf][o];
#pragma unroll
            for (int c = 0; c < 4; ++c)
                acc[c] = __builtin_amdgcn_mfma_f32_16x16x32_f16(afrag, breg[ks][c],
                                                                acc[c], 0, 0, 0);
        }

        // epilogue: bias (+relu), store C  (C/D map: col=lane&15, row=(lane>>4)*4+r)
        {
            int row0 = t * 32;
#pragma unroll
            for (int c = 0; c < 4; ++c) {
                int col = wcol * 64 + c * 16 + (lane & 15);
#pragma unroll
                for (int r = 0; r < 4; ++r) {
                    int row = row0 + wrow * 16 + (lane >> 4) * 4 + r;
                    float o = acc[c][r] + bv[c];
                    if (relu) o = fmaxf(o, 0.f);
                    out[(size_t)row * D + col] = o;
                }
            }
        }

        __syncthreads();   // all waves done reading sA[buf^1] (previous iter)
        if (havenext) {
#pragma unroll
            for (int it = 0; it < 8; ++it) {
                int i = it * 256 + tid, r = i >> 6, k4 = i & 63;
                float4 v = sreg[it];
                f16x4 hv;
                hv[0] = (f16)v.x; hv[1] = (f16)v.y; hv[2] = (f16)v.z; hv[3] = (f16)v.w;
                int o = (r * 256 + k4 * 4) ^ ((r & 7) << 3);
                *(f16x4*)&sA[buf ^ 1][o] = hv;
            }
        }
        __syncthreads();
        buf ^= 1;
    }
}

// ---------------- launch ----------------

extern "C" void kernel_launch(void* const* d_in, const int* in_sizes, int n_in,
                              void* d_out, int out_size, void* d_ws, size_t ws_size,
                              hipStream_t stream) {
    const float* x  = (const float*)d_in[0];
    const float* ew = (const float*)d_in[1];
    const float* W_rel[3]  = {(const float*)d_in[2], (const float*)d_in[5], (const float*)d_in[8]};
    const float* W_root[3] = {(const float*)d_in[3], (const float*)d_in[6], (const float*)d_in[9]};
    const float* bias[3]   = {(const float*)d_in[4], (const float*)d_in[7], (const float*)d_in[10]};
    const int* esrc = (const int*)d_in[11];
    const int* edst = (const int*)d_in[12];
    float* out = (float*)d_out;

    char* ws = (char*)d_ws;
    float* agg       = (float*)(ws);                 // 51,200,000 B
    float* h1        = (float*)(ws + 51200000);      // 51,200,000 B
    int2*  csr_sw    = (int2*) (ws + 102400000);     // 12,800,000 B
    int*   row_ptr   = (int*)  (ws + 115200000);     //    400,016 B
    int*   cursor    = (int*)  (ws + 115600016);     //    400,000 B
    int*   blockSums = (int*)  (ws + 116000016);     //        512 B
    f16*   Bp        = (f16*)  (ws + 116000528);     //    196,608 B (3 x 32768 f16)

    // CSR build (reused by all 3 layers)
    hipMemsetAsync(cursor, 0, N_NODES * sizeof(int), stream);
    hist_kernel<<<N_EDGES / 256, 256, 0, stream>>>(edst, cursor);
    scanA<<<98, 256, 0, stream>>>(cursor, row_ptr, blockSums);
    scanB<<<1, 64, 0, stream>>>(blockSums, 98);
    scanC<<<98, 256, 0, stream>>>(row_ptr, blockSums);
    hipMemsetAsync(cursor, 0, N_NODES * sizeof(int), stream);
    fill_kernel<<<N_EDGES / 256, 256, 0, stream>>>(esrc, edst, ew, row_ptr, cursor, csr_sw);

    // weight packs (f16 B-fragment layout)
    for (int l = 0; l < 3; ++l)
        pack_weights<<<128, 256, 0, stream>>>(W_rel[l], W_root[l], Bp + l * 32768);

    // 3 GraphConv layers
    const float* hin = x;
    for (int l = 0; l < 3; ++l) {
        float* hout = (l == 0) ? h1 : out;
        aggregate_kernel<<<N_NODES / 4, 256, 0, stream>>>(hin, row_ptr, csr_sw, agg);
        gemm_mfma<<<GEMM_GRID, 256, 0, stream>>>(agg, hin, (const f16x8*)(Bp + l * 32768),
                                                 bias[l], hout, (l < 2) ? 1 : 0);
        hin = hout;
    }
}

// Round 4
// 582.900 us; speedup vs baseline: 1.7795x; 1.0604x over previous
//
#include <hip/hip_runtime.h>

#define N_NODES 100000
#define N_EDGES 1600000
#define D 128
#define N_TILES 3125        // N_NODES / 32
#define GEMM_GRID 512

typedef _Float16 f16;
typedef _Float16 f16x8 __attribute__((ext_vector_type(8)));
typedef _Float16 f16x2 __attribute__((ext_vector_type(2)));
typedef float f32x4 __attribute__((ext_vector_type(4)));

// ---------------- CSR build ----------------

__global__ __launch_bounds__(256) void hist_kernel(const int* __restrict__ dst,
                                                   int* __restrict__ counts) {
    int e = blockIdx.x * 256 + threadIdx.x;   // grid exactly N_EDGES
    atomicAdd(&counts[dst[e]], 1);
}

__global__ __launch_bounds__(256) void scanA(const int* __restrict__ counts,
                                             int* __restrict__ row_ptr,
                                             int* __restrict__ blockSums) {
    __shared__ int sc[256];
    int tid  = threadIdx.x;
    int base = blockIdx.x * 1024 + tid * 4;
    int v[4];
#pragma unroll
    for (int k = 0; k < 4; ++k) {
        int i = base + k;
        v[k] = (i < N_NODES) ? counts[i] : 0;
    }
    int s = v[0] + v[1] + v[2] + v[3];
    sc[tid] = s;
    __syncthreads();
    for (int off = 1; off < 256; off <<= 1) {
        int t = (tid >= off) ? sc[tid - off] : 0;
        __syncthreads();
        sc[tid] += t;
        __syncthreads();
    }
    int run = sc[tid] - s;
#pragma unroll
    for (int k = 0; k < 4; ++k) {
        int i = base + k;
        if (i < N_NODES) row_ptr[i] = run;
        run += v[k];
    }
    if (tid == 255) blockSums[blockIdx.x] = sc[255];
}

__global__ void scanB(int* blockSums, int nb) {
    if (threadIdx.x == 0 && blockIdx.x == 0) {
        int run = 0;
        for (int b = 0; b < nb; ++b) {
            int t = blockSums[b];
            blockSums[b] = run;
            run += t;
        }
    }
}

__global__ __launch_bounds__(256) void scanC(int* __restrict__ row_ptr,
                                             const int* __restrict__ blockSums) {
    int tid  = threadIdx.x;
    int base = blockIdx.x * 1024 + tid * 4;
    int add  = blockSums[blockIdx.x];
#pragma unroll
    for (int k = 0; k < 4; ++k) {
        int i = base + k;
        if (i < N_NODES) row_ptr[i] += add;
    }
    if (blockIdx.x == 0 && tid == 0) row_ptr[N_NODES] = N_EDGES;
}

// csr_sw[p] = (src, float_as_int(w))
__global__ __launch_bounds__(256) void fill_kernel(const int* __restrict__ src,
                                                   const int* __restrict__ dst,
                                                   const float* __restrict__ w,
                                                   const int* __restrict__ row_ptr,
                                                   int* __restrict__ cursor,
                                                   int2* __restrict__ csr_sw) {
    int e = blockIdx.x * 256 + threadIdx.x;   // grid exactly N_EDGES
    int d = dst[e];
    int p = row_ptr[d] + atomicAdd(&cursor[d], 1);
    csr_sw[p] = make_int2(src[e], __float_as_int(w[e]));
}

// ---------------- fp32 -> f16 convert (x only, once) ----------------

__global__ __launch_bounds__(256) void cvt_f32_f16(const float* __restrict__ in,
                                                   f16* __restrict__ out) {
    int i = blockIdx.x * 256 + threadIdx.x;   // grid 6250: 8 elems/thread
    const float4* in4 = (const float4*)in;
    float4 a = in4[i * 2], b = in4[i * 2 + 1];
    f16x8 v;
    v[0] = (f16)a.x; v[1] = (f16)a.y; v[2] = (f16)a.z; v[3] = (f16)a.w;
    v[4] = (f16)b.x; v[5] = (f16)b.y; v[6] = (f16)b.z; v[7] = (f16)b.w;
    ((f16x8*)out)[i] = v;
}

// ---------------- weight pack: B-fragment layout, f16 ----------------
// Bp element ((ks*8 + ct)*64 + lane)*8 + e = W[j][k] with
// j = ct*16 + (lane&15), k = ks*32 + (lane>>4)*8 + e  (k<128 -> Wrel, else Wroot)

__global__ __launch_bounds__(256) void pack_weights(const float* __restrict__ Wrel,
                                                    const float* __restrict__ Wroot,
                                                    f16* __restrict__ Bp) {
    int idx = blockIdx.x * 256 + threadIdx.x;   // 32768 total -> 128 blocks
    int e = idx & 7, lane = (idx >> 3) & 63, ct = (idx >> 9) & 7, ks = idx >> 12;
    int j = ct * 16 + (lane & 15);
    int k = ks * 32 + (lane >> 4) * 8 + e;
    float w = (k < D) ? Wrel[j * D + k] : Wroot[j * D + (k - D)];
    Bp[idx] = (f16)w;
}

// ---------------- aggregation: one wave per node, 16 gathers in flight ----------------

__global__ __launch_bounds__(256) void aggregate_kernel(const f16* __restrict__ h,
                                                        const int* __restrict__ row_ptr,
                                                        const int2* __restrict__ csr_sw,
                                                        f16* __restrict__ agg) {
    int node = blockIdx.x * 4 + (threadIdx.x >> 6);   // grid*4 == N_NODES exactly
    int lane = threadIdx.x & 63;
    int beg = row_ptr[node], end = row_ptr[node + 1];
    const f16x2* h2 = (const f16x2*)h;   // lane covers channels 2l, 2l+1

    float ax0 = 0.f, ay0 = 0.f, ax1 = 0.f, ay1 = 0.f;

    int e = beg;
    for (; e + 16 <= end; e += 16) {
        int2 p[16];
#pragma unroll
        for (int k = 0; k < 16; ++k) p[k] = csr_sw[e + k];
        f16x2 v[16];
#pragma unroll
        for (int k = 0; k < 16; ++k) v[k] = h2[(size_t)p[k].x * 64 + lane];
#pragma unroll
        for (int k = 0; k < 16; ++k) {
            float w = __int_as_float(p[k].y);
            if (k & 1) {
                ax1 = fmaf(w, (float)v[k][0], ax1);
                ay1 = fmaf(w, (float)v[k][1], ay1);
            } else {
                ax0 = fmaf(w, (float)v[k][0], ax0);
                ay0 = fmaf(w, (float)v[k][1], ay0);
            }
        }
    }
    {   // tail (up to 15 edges): batch-issue loads before consuming
        int rem = end - e;
        int2  p[15];
        f16x2 v[15];
#pragma unroll
        for (int k = 0; k < 15; ++k)
            if (k < rem) p[k] = csr_sw[e + k];
#pragma unroll
        for (int k = 0; k < 15; ++k)
            if (k < rem) v[k] = h2[(size_t)p[k].x * 64 + lane];
#pragma unroll
        for (int k = 0; k < 15; ++k)
            if (k < rem) {
                float w = __int_as_float(p[k].y);
                ax0 = fmaf(w, (float)v[k][0], ax0);
                ay0 = fmaf(w, (float)v[k][1], ay0);
            }
    }
    f16x2 o;
    o[0] = (f16)(ax0 + ax1);
    o[1] = (f16)(ay0 + ay1);
    ((f16x2*)agg)[(size_t)node * 64 + lane] = o;
}

// ---------------- MFMA GEMM: out = [agg|h] @ Bp + bias (+ReLU) ----------------
// 256 thr = 4 waves (2 row x 2 col). Wave owns 16 rows x 64 cols.
// B-frags in registers. A (f16) staged in LDS, XOR-swizzled, double-buffered.
// FINAL=0: f16 out + ReLU.  FINAL=1: fp32 out, no ReLU.

template <int FINAL>
__global__ __launch_bounds__(256, 2) void gemm_mfma(const f16* __restrict__ agg,
                                                    const f16* __restrict__ h,
                                                    const f16x8* __restrict__ Bp,
                                                    const float* __restrict__ bias,
                                                    void* __restrict__ outp) {
    __shared__ f16 sA[2][32 * 256];   // 2 x 16 KB
    int tid  = threadIdx.x;
    int lane = tid & 63;
    int wid  = tid >> 6;
    int wrow = wid >> 1;              // rows [wrow*16, +16)
    int wcol = wid & 1;               // cols [wcol*64, +64)

    // B fragments: 8 k-steps x 4 col-tiles, loaded once (L2-hot)
    f16x8 breg[8][4];
#pragma unroll
    for (int ks = 0; ks < 8; ++ks)
#pragma unroll
        for (int c = 0; c < 4; ++c)
            breg[ks][c] = Bp[(ks * 8 + wcol * 4 + c) * 64 + lane];

    float bv[4];
#pragma unroll
    for (int c = 0; c < 4; ++c) bv[c] = bias[wcol * 64 + c * 16 + (lane & 15)];

    const uint4* a16 = (const uint4*)agg;   // 8 f16 per uint4; 16 chunks/row
    const uint4* h16 = (const uint4*)h;

    // prologue: stage first tile into buf 0 (1024 x 16B chunks, 4 iters)
    {
        int row0 = blockIdx.x * 32;
#pragma unroll
        for (int it = 0; it < 4; ++it) {
            int i = it * 256 + tid, r = i >> 5, c8 = i & 31;
            uint4 v = (c8 < 16) ? a16[(row0 + r) * 16 + c8]
                                : h16[(row0 + r) * 16 + (c8 - 16)];
            int o = (r * 256 + c8 * 8) ^ ((r & 7) << 3);
            *(uint4*)&sA[0][o] = v;
        }
    }
    __syncthreads();

    int buf = 0;
    for (int t = blockIdx.x; t < N_TILES; t += GEMM_GRID) {
        int  tn = t + GEMM_GRID;
        bool havenext = (tn < N_TILES);

        // issue next tile's global loads early (latency hides under MFMA)
        uint4 sreg[4];
        if (havenext) {
            int row0 = tn * 32;
#pragma unroll
            for (int it = 0; it < 4; ++it) {
                int i = it * 256 + tid, r = i >> 5, c8 = i & 31;
                sreg[it] = (c8 < 16) ? a16[(row0 + r) * 16 + c8]
                                     : h16[(row0 + r) * 16 + (c8 - 16)];
            }
        }

        // compute tile t from sA[buf]
        f32x4 acc[4] = {f32x4{0,0,0,0}, f32x4{0,0,0,0}, f32x4{0,0,0,0}, f32x4{0,0,0,0}};
        int arow = wrow * 16 + (lane & 15);
        int kg   = (lane >> 4) * 8;
#pragma unroll
        for (int ks = 0; ks < 8; ++ks) {
            int o = (arow * 256 + ks * 32 + kg) ^ ((arow & 7) << 3);
            f16x8 afrag = *(const f16x8*)&sA[buf][o];
#pragma unroll
            for (int c = 0; c < 4; ++c)
                acc[c] = __builtin_amdgcn_mfma_f32_16x16x32_f16(afrag, breg[ks][c],
                                                                acc[c], 0, 0, 0);
        }

        // epilogue: bias (+relu), store C  (C/D map: col=lane&15, row=(lane>>4)*4+r)
        {
            int row0 = t * 32;
#pragma unroll
            for (int c = 0; c < 4; ++c) {
                int col = wcol * 64 + c * 16 + (lane & 15);
#pragma unroll
                for (int r = 0; r < 4; ++r) {
                    int row = row0 + wrow * 16 + (lane >> 4) * 4 + r;
                    float o = acc[c][r] + bv[c];
                    if (FINAL) {
                        ((float*)outp)[(size_t)row * D + col] = o;
                    } else {
                        ((f16*)outp)[(size_t)row * D + col] = (f16)fmaxf(o, 0.f);
                    }
                }
            }
        }

        __syncthreads();   // all waves done reading sA[buf^1] (previous iter)
        if (havenext) {
#pragma unroll
            for (int it = 0; it < 4; ++it) {
                int i = it * 256 + tid, r = i >> 5, c8 = i & 31;
                int o = (r * 256 + c8 * 8) ^ ((r & 7) << 3);
                *(uint4*)&sA[buf ^ 1][o] = sreg[it];
            }
        }
        __syncthreads();
        buf ^= 1;
    }
}

// ---------------- launch ----------------

extern "C" void kernel_launch(void* const* d_in, const int* in_sizes, int n_in,
                              void* d_out, int out_size, void* d_ws, size_t ws_size,
                              hipStream_t stream) {
    const float* x  = (const float*)d_in[0];
    const float* ew = (const float*)d_in[1];
    const float* W_rel[3]  = {(const float*)d_in[2], (const float*)d_in[5], (const float*)d_in[8]};
    const float* W_root[3] = {(const float*)d_in[3], (const float*)d_in[6], (const float*)d_in[9]};
    const float* bias[3]   = {(const float*)d_in[4], (const float*)d_in[7], (const float*)d_in[10]};
    const int* esrc = (const int*)d_in[11];
    const int* edst = (const int*)d_in[12];

    char* ws = (char*)d_ws;
    f16*   agg16     = (f16*)  (ws);                 // 25,600,000 B
    f16*   bufA      = (f16*)  (ws + 25600000);      // 25,600,000 B (x16, then layer1 out)
    f16*   bufB      = (f16*)  (ws + 51200000);      // 25,600,000 B (layer0 out)
    int2*  csr_sw    = (int2*) (ws + 76800000);      // 12,800,000 B
    int*   row_ptr   = (int*)  (ws + 89600000);      //    400,016 B
    int*   cursor    = (int*)  (ws + 90000016);      //    400,000 B
    int*   blockSums = (int*)  (ws + 90400016);      //        512 B
    f16*   Bp        = (f16*)  (ws + 90400528);      //    196,608 B (3 x 32768 f16)

    // CSR build (reused by all 3 layers)
    hipMemsetAsync(cursor, 0, N_NODES * sizeof(int), stream);
    hist_kernel<<<N_EDGES / 256, 256, 0, stream>>>(edst, cursor);
    scanA<<<98, 256, 0, stream>>>(cursor, row_ptr, blockSums);
    scanB<<<1, 64, 0, stream>>>(blockSums, 98);
    scanC<<<98, 256, 0, stream>>>(row_ptr, blockSums);
    hipMemsetAsync(cursor, 0, N_NODES * sizeof(int), stream);
    fill_kernel<<<N_EDGES / 256, 256, 0, stream>>>(esrc, edst, ew, row_ptr, cursor, csr_sw);

    // x -> f16, weight packs
    cvt_f32_f16<<<6250, 256, 0, stream>>>(x, bufA);
    for (int l = 0; l < 3; ++l)
        pack_weights<<<128, 256, 0, stream>>>(W_rel[l], W_root[l], Bp + l * 32768);

    // layer 0: bufA -> bufB (f16, relu)
    aggregate_kernel<<<N_NODES / 4, 256, 0, stream>>>(bufA, row_ptr, csr_sw, agg16);
    gemm_mfma<0><<<GEMM_GRID, 256, 0, stream>>>(agg16, bufA, (const f16x8*)(Bp + 0 * 32768),
                                                bias[0], bufB);
    // layer 1: bufB -> bufA (f16, relu)
    aggregate_kernel<<<N_NODES / 4, 256, 0, stream>>>(bufB, row_ptr, csr_sw, agg16);
    gemm_mfma<0><<<GEMM_GRID, 256, 0, stream>>>(agg16, bufB, (const f16x8*)(Bp + 1 * 32768),
                                                bias[1], bufA);
    // layer 2: bufA -> d_out (fp32, no relu)
    aggregate_kernel<<<N_NODES / 4, 256, 0, stream>>>(bufA, row_ptr, csr_sw, agg16);
    gemm_mfma<1><<<GEMM_GRID, 256, 0, stream>>>(agg16, bufA, (const f16x8*)(Bp + 2 * 32768),
                                                bias[2], d_out);
}

// Round 5
// 452.984 us; speedup vs baseline: 2.2898x; 1.2868x over previous
//
#include <hip/hip_runtime.h>

#define N_NODES 100000
#define N_EDGES 1600000
#define D 128
#define N_TILES 3125        // N_NODES / 32
#define GEMM_GRID 512

typedef _Float16 f16;
typedef _Float16 f16x8 __attribute__((ext_vector_type(8)));
typedef _Float16 f16x2 __attribute__((ext_vector_type(2)));
typedef float f32x4 __attribute__((ext_vector_type(4)));

// ---------------- CSR build ----------------

__global__ __launch_bounds__(256) void hist_kernel(const int* __restrict__ dst,
                                                   int* __restrict__ counts) {
    int e = blockIdx.x * 256 + threadIdx.x;   // grid exactly N_EDGES
    atomicAdd(&counts[dst[e]], 1);
}

__global__ __launch_bounds__(256) void scanA(const int* __restrict__ counts,
                                             int* __restrict__ row_ptr,
                                             int* __restrict__ blockSums) {
    __shared__ int sc[256];
    int tid  = threadIdx.x;
    int base = blockIdx.x * 1024 + tid * 4;
    int v[4];
#pragma unroll
    for (int k = 0; k < 4; ++k) {
        int i = base + k;
        v[k] = (i < N_NODES) ? counts[i] : 0;
    }
    int s = v[0] + v[1] + v[2] + v[3];
    sc[tid] = s;
    __syncthreads();
    for (int off = 1; off < 256; off <<= 1) {
        int t = (tid >= off) ? sc[tid - off] : 0;
        __syncthreads();
        sc[tid] += t;
        __syncthreads();
    }
    int run = sc[tid] - s;
#pragma unroll
    for (int k = 0; k < 4; ++k) {
        int i = base + k;
        if (i < N_NODES) row_ptr[i] = run;
        run += v[k];
    }
    if (tid == 255) blockSums[blockIdx.x] = sc[255];
}

__global__ void scanB(int* blockSums, int nb) {
    if (threadIdx.x == 0 && blockIdx.x == 0) {
        int run = 0;
        for (int b = 0; b < nb; ++b) {
            int t = blockSums[b];
            blockSums[b] = run;
            run += t;
        }
    }
}

__global__ __launch_bounds__(256) void scanC(int* __restrict__ row_ptr,
                                             const int* __restrict__ blockSums) {
    int tid  = threadIdx.x;
    int base = blockIdx.x * 1024 + tid * 4;
    int add  = blockSums[blockIdx.x];
#pragma unroll
    for (int k = 0; k < 4; ++k) {
        int i = base + k;
        if (i < N_NODES) row_ptr[i] += add;
    }
    if (blockIdx.x == 0 && tid == 0) row_ptr[N_NODES] = N_EDGES;
}

// csr[p] = (src << 15) | round(w * 32767)   (one u32 per edge)
__global__ __launch_bounds__(256) void fill_kernel(const int* __restrict__ src,
                                                   const int* __restrict__ dst,
                                                   const float* __restrict__ w,
                                                   const int* __restrict__ row_ptr,
                                                   int* __restrict__ cursor,
                                                   unsigned* __restrict__ csr) {
    int e = blockIdx.x * 256 + threadIdx.x;   // grid exactly N_EDGES
    int d = dst[e];
    int p = row_ptr[d] + atomicAdd(&cursor[d], 1);
    unsigned wq = (unsigned)rintf(w[e] * 32767.0f);
    csr[p] = ((unsigned)src[e] << 15) | wq;
}

// ---------------- fp32 -> f16 convert (x only, once) ----------------

__global__ __launch_bounds__(256) void cvt_f32_f16(const float* __restrict__ in,
                                                   f16* __restrict__ out) {
    int i = blockIdx.x * 256 + threadIdx.x;   // grid 6250: 8 elems/thread
    const float4* in4 = (const float4*)in;
    float4 a = in4[i * 2], b = in4[i * 2 + 1];
    f16x8 v;
    v[0] = (f16)a.x; v[1] = (f16)a.y; v[2] = (f16)a.z; v[3] = (f16)a.w;
    v[4] = (f16)b.x; v[5] = (f16)b.y; v[6] = (f16)b.z; v[7] = (f16)b.w;
    ((f16x8*)out)[i] = v;
}

// ---------------- weight pack: B-fragment layout, f16 ----------------
// Bp element ((ks*8 + ct)*64 + lane)*8 + e = W[j][k] with
// j = ct*16 + (lane&15), k = ks*32 + (lane>>4)*8 + e  (k<128 -> Wrel, else Wroot)

__global__ __launch_bounds__(256) void pack_weights(const float* __restrict__ Wrel,
                                                    const float* __restrict__ Wroot,
                                                    f16* __restrict__ Bp) {
    int idx = blockIdx.x * 256 + threadIdx.x;   // 32768 total -> 128 blocks
    int e = idx & 7, lane = (idx >> 3) & 63, ct = (idx >> 9) & 7, ks = idx >> 12;
    int j = ct * 16 + (lane & 15);
    int k = ks * 32 + (lane >> 4) * 8 + e;
    float w = (k < D) ? Wrel[j * D + k] : Wroot[j * D + (k - D)];
    Bp[idx] = (f16)w;
}

// ---------------- aggregation: one wave/node, readlane CSR, pinned 16-deep MLP ----

__global__ __launch_bounds__(256) void aggregate_kernel(const f16* __restrict__ h,
                                                        const int* __restrict__ row_ptr,
                                                        const unsigned* __restrict__ csr,
                                                        f16* __restrict__ agg) {
    int node = blockIdx.x * 4 + (threadIdx.x >> 6);   // grid*4 == N_NODES exactly
    int lane = threadIdx.x & 63;
    int li   = lane & 15;
    int beg = row_ptr[node], end = row_ptr[node + 1];
    const f16x2* h2 = (const f16x2*)h;   // lane covers channels 2l, 2l+1

    float ax0 = 0.f, ay0 = 0.f, ax1 = 0.f, ay1 = 0.f;

    int e = beg;
    for (; e + 16 <= end; e += 16) {
        // lanes 0-15 fetch 16 packed edges in one 64B load (quarters duplicate)
        unsigned pv = csr[e + li];
        __builtin_amdgcn_sched_barrier(0);
        f16x2 gv[16];
        float gw[16];
#pragma unroll
        for (int k = 0; k < 16; ++k) {
            unsigned s = __builtin_amdgcn_readlane(pv, k);   // uniform -> SGPR
            gw[k] = (float)(s & 0x7fffu) * (1.0f / 32767.0f);
            gv[k] = h2[(size_t)(s >> 15) * 64 + lane];       // saddr gather, 256B/wave
        }
        __builtin_amdgcn_sched_barrier(0);   // keep all 16 gathers in flight
#pragma unroll
        for (int k = 0; k < 16; ++k) {
            float vx = (float)gv[k][0], vy = (float)gv[k][1];
            if (k & 1) { ax1 = fmaf(gw[k], vx, ax1); ay1 = fmaf(gw[k], vy, ay1); }
            else       { ax0 = fmaf(gw[k], vx, ax0); ay0 = fmaf(gw[k], vy, ay0); }
        }
    }
    if (e < end) {   // masked tail chunk: clamped index, zeroed weights
        int rem = end - e;
        int idx = e + li, em1 = end - 1;
        idx = idx < em1 ? idx : em1;
        unsigned pv = csr[idx];
        __builtin_amdgcn_sched_barrier(0);
        f16x2 gv[16];
        float gw[16];
#pragma unroll
        for (int k = 0; k < 16; ++k) {
            unsigned s = __builtin_amdgcn_readlane(pv, k);
            gw[k] = (k < rem) ? (float)(s & 0x7fffu) * (1.0f / 32767.0f) : 0.f;
            gv[k] = h2[(size_t)(s >> 15) * 64 + lane];
        }
        __builtin_amdgcn_sched_barrier(0);
#pragma unroll
        for (int k = 0; k < 16; ++k) {
            float vx = (float)gv[k][0], vy = (float)gv[k][1];
            if (k & 1) { ax1 = fmaf(gw[k], vx, ax1); ay1 = fmaf(gw[k], vy, ay1); }
            else       { ax0 = fmaf(gw[k], vx, ax0); ay0 = fmaf(gw[k], vy, ay0); }
        }
    }
    f16x2 o;
    o[0] = (f16)(ax0 + ax1);
    o[1] = (f16)(ay0 + ay1);
    ((f16x2*)agg)[(size_t)node * 64 + lane] = o;
}

// ---------------- MFMA GEMM: out = [agg|h] @ Bp + bias (+ReLU) ----------------
// 256 thr = 4 waves (2 row x 2 col). Wave owns 16 rows x 64 cols.
// B-frags in registers. A (f16) staged in LDS, XOR-swizzled, double-buffered.
// FINAL=0: f16 out + ReLU.  FINAL=1: fp32 out, no ReLU.

template <int FINAL>
__global__ __launch_bounds__(256, 2) void gemm_mfma(const f16* __restrict__ agg,
                                                    const f16* __restrict__ h,
                                                    const f16x8* __restrict__ Bp,
                                                    const float* __restrict__ bias,
                                                    void* __restrict__ outp) {
    __shared__ f16 sA[2][32 * 256];   // 2 x 16 KB
    int tid  = threadIdx.x;
    int lane = tid & 63;
    int wid  = tid >> 6;
    int wrow = wid >> 1;              // rows [wrow*16, +16)
    int wcol = wid & 1;               // cols [wcol*64, +64)

    // B fragments: 8 k-steps x 4 col-tiles, loaded once (L2-hot)
    f16x8 breg[8][4];
#pragma unroll
    for (int ks = 0; ks < 8; ++ks)
#pragma unroll
        for (int c = 0; c < 4; ++c)
            breg[ks][c] = Bp[(ks * 8 + wcol * 4 + c) * 64 + lane];

    float bv[4];
#pragma unroll
    for (int c = 0; c < 4; ++c) bv[c] = bias[wcol * 64 + c * 16 + (lane & 15)];

    const uint4* a16 = (const uint4*)agg;   // 8 f16 per uint4; 16 chunks/row
    const uint4* h16 = (const uint4*)h;

    // prologue: stage first tile into buf 0 (1024 x 16B chunks, 4 iters)
    {
        int row0 = blockIdx.x * 32;
#pragma unroll
        for (int it = 0; it < 4; ++it) {
            int i = it * 256 + tid, r = i >> 5, c8 = i & 31;
            uint4 v = (c8 < 16) ? a16[(row0 + r) * 16 + c8]
                                : h16[(row0 + r) * 16 + (c8 - 16)];
            int o = (r * 256 + c8 * 8) ^ ((r & 7) << 3);
            *(uint4*)&sA[0][o] = v;
        }
    }
    __syncthreads();

    int buf = 0;
    for (int t = blockIdx.x; t < N_TILES; t += GEMM_GRID) {
        int  tn = t + GEMM_GRID;
        bool havenext = (tn < N_TILES);

        // issue next tile's global loads early (latency hides under MFMA)
        uint4 sreg[4];
        if (havenext) {
            int row0 = tn * 32;
#pragma unroll
            for (int it = 0; it < 4; ++it) {
                int i = it * 256 + tid, r = i >> 5, c8 = i & 31;
                sreg[it] = (c8 < 16) ? a16[(row0 + r) * 16 + c8]
                                     : h16[(row0 + r) * 16 + (c8 - 16)];
            }
        }

        // compute tile t from sA[buf]
        f32x4 acc[4] = {f32x4{0,0,0,0}, f32x4{0,0,0,0}, f32x4{0,0,0,0}, f32x4{0,0,0,0}};
        int arow = wrow * 16 + (lane & 15);
        int kg   = (lane >> 4) * 8;
#pragma unroll
        for (int ks = 0; ks < 8; ++ks) {
            int o = (arow * 256 + ks * 32 + kg) ^ ((arow & 7) << 3);
            f16x8 afrag = *(const f16x8*)&sA[buf][o];
#pragma unroll
            for (int c = 0; c < 4; ++c)
                acc[c] = __builtin_amdgcn_mfma_f32_16x16x32_f16(afrag, breg[ks][c],
                                                                acc[c], 0, 0, 0);
        }

        // epilogue: bias (+relu), store C  (C/D map: col=lane&15, row=(lane>>4)*4+r)
        {
            int row0 = t * 32;
#pragma unroll
            for (int c = 0; c < 4; ++c) {
                int col = wcol * 64 + c * 16 + (lane & 15);
#pragma unroll
                for (int r = 0; r < 4; ++r) {
                    int row = row0 + wrow * 16 + (lane >> 4) * 4 + r;
                    float o = acc[c][r] + bv[c];
                    if (FINAL) {
                        ((float*)outp)[(size_t)row * D + col] = o;
                    } else {
                        ((f16*)outp)[(size_t)row * D + col] = (f16)fmaxf(o, 0.f);
                    }
                }
            }
        }

        __syncthreads();   // all waves done reading sA[buf^1] (previous iter)
        if (havenext) {
#pragma unroll
            for (int it = 0; it < 4; ++it) {
                int i = it * 256 + tid, r = i >> 5, c8 = i & 31;
                int o = (r * 256 + c8 * 8) ^ ((r & 7) << 3);
                *(uint4*)&sA[buf ^ 1][o] = sreg[it];
            }
        }
        __syncthreads();
        buf ^= 1;
    }
}

// ---------------- launch ----------------

extern "C" void kernel_launch(void* const* d_in, const int* in_sizes, int n_in,
                              void* d_out, int out_size, void* d_ws, size_t ws_size,
                              hipStream_t stream) {
    const float* x  = (const float*)d_in[0];
    const float* ew = (const float*)d_in[1];
    const float* W_rel[3]  = {(const float*)d_in[2], (const float*)d_in[5], (const float*)d_in[8]};
    const float* W_root[3] = {(const float*)d_in[3], (const float*)d_in[6], (const float*)d_in[9]};
    const float* bias[3]   = {(const float*)d_in[4], (const float*)d_in[7], (const float*)d_in[10]};
    const int* esrc = (const int*)d_in[11];
    const int* edst = (const int*)d_in[12];

    char* ws = (char*)d_ws;
    f16*      agg16     = (f16*)     (ws);               // 25,600,000 B
    f16*      bufA      = (f16*)     (ws + 25600000);    // 25,600,000 B
    f16*      bufB      = (f16*)     (ws + 51200000);    // 25,600,000 B
    unsigned* csr       = (unsigned*)(ws + 76800000);    //  6,400,000 B
    int*      row_ptr   = (int*)     (ws + 83200000);    //    400,016 B
    int*      cursor    = (int*)     (ws + 83600016);    //    400,000 B
    int*      blockSums = (int*)     (ws + 84000016);    //        512 B
    f16*      Bp        = (f16*)     (ws + 84000528);    //    196,608 B

    // CSR build (reused by all 3 layers)
    hipMemsetAsync(cursor, 0, N_NODES * sizeof(int), stream);
    hist_kernel<<<N_EDGES / 256, 256, 0, stream>>>(edst, cursor);
    scanA<<<98, 256, 0, stream>>>(cursor, row_ptr, blockSums);
    scanB<<<1, 64, 0, stream>>>(blockSums, 98);
    scanC<<<98, 256, 0, stream>>>(row_ptr, blockSums);
    hipMemsetAsync(cursor, 0, N_NODES * sizeof(int), stream);
    fill_kernel<<<N_EDGES / 256, 256, 0, stream>>>(esrc, edst, ew, row_ptr, cursor, csr);

    // x -> f16, weight packs
    cvt_f32_f16<<<6250, 256, 0, stream>>>(x, bufA);
    for (int l = 0; l < 3; ++l)
        pack_weights<<<128, 256, 0, stream>>>(W_rel[l], W_root[l], Bp + l * 32768);

    // layer 0: bufA -> bufB (f16, relu)
    aggregate_kernel<<<N_NODES / 4, 256, 0, stream>>>(bufA, row_ptr, csr, agg16);
    gemm_mfma<0><<<GEMM_GRID, 256, 0, stream>>>(agg16, bufA, (const f16x8*)(Bp + 0 * 32768),
                                                bias[0], bufB);
    // layer 1: bufB -> bufA (f16, relu)
    aggregate_kernel<<<N_NODES / 4, 256, 0, stream>>>(bufB, row_ptr, csr, agg16);
    gemm_mfma<0><<<GEMM_GRID, 256, 0, stream>>>(agg16, bufB, (const f16x8*)(Bp + 1 * 32768),
                                                bias[1], bufA);
    // layer 2: bufA -> d_out (fp32, no relu)
    aggregate_kernel<<<N_NODES / 4, 256, 0, stream>>>(bufA, row_ptr, csr, agg16);
    gemm_mfma<1><<<GEMM_GRID, 256, 0, stream>>>(agg16, bufA, (const f16x8*)(Bp + 2 * 32768),
                                                bias[2], d_out);
}